// Round 4
// baseline (1504.265 us; speedup 1.0000x reference)
//
#include <hip/hip_runtime.h>
#include <hip/hip_bf16.h>

#define BATCH  16
#define CCH    128
#define TDIM   16384
#define MROWS  256                 // 2C
#define NCHUNK 32                  // 512 blocks -> 2 blocks/CU
#define KC     (TDIM / NCHUNK)     // 512
#define BK     32
#define NSTEP  (KC / BK)           // 16
#define LDSP   40                  // padded LDS row stride (bf16): 80 B
#define GRAM   (MROWS * MROWS)     // 65536

// ws layout (floats): [norms 4096][diag 16*32*256][body partials]
#define WS_NORMS 0
#define WS_DIAG  4096
#define WS_BODY  (4096 + BATCH * NCHUNK * MROWS)   // 4096 + 131072

typedef __attribute__((ext_vector_type(8))) short bf16x8;
typedef __attribute__((ext_vector_type(4))) float f32x4;
typedef __attribute__((ext_vector_type(8))) unsigned short u16x8;

__device__ __forceinline__ unsigned short f2bf(float x) {
  unsigned int u = __float_as_uint(x);
  u += 0x7fffu + ((u >> 16) & 1u);
  return (unsigned short)(u >> 16);
}

// Partial gram of M_b = [s_b; t_b] (256 x T) over one K-chunk (KC cols).
// slot = chunk >> slot_shift; nslots = NCHUNK >> slot_shift.
// atomic=0 (slot_shift==0): plain stores. atomic=1: atomicAdd (slots shared).
__global__ __launch_bounds__(512, 4) void gram_kernel(
    const float* __restrict__ fs, const float* __restrict__ ft,
    float* __restrict__ outp, float* __restrict__ diagp,
    int slot_shift, int atomic)
{
  __shared__ __attribute__((aligned(16))) unsigned short sm[2][MROWS][LDSP];

  const int tid   = threadIdx.x;
  const int bidx  = blockIdx.x;
  const int b     = bidx / NCHUNK;
  const int chunk = bidx - b * NCHUNK;
  const int kbase = chunk * KC;
  const int nslots = NCHUNK >> slot_shift;
  const int sbase  = b * nslots + (chunk >> slot_shift);

  const int lane = tid & 63;
  const int w    = tid >> 6;     // wave 0..7
  const int wr   = w & 3;        // rows [wr*64, +64)
  const int wc   = w >> 2;       // cols [wc*128, +128)
  const int lhi  = lane >> 4;
  const int llo  = lane & 15;
  const int koff = lhi * 8;      // bf16 elems (16 B)

  // staging: 2 threads per row, 64 B contiguous per thread per step
  const int srow = tid >> 1;
  const int half = tid & 1;
  const float* rp = ((srow < CCH)
      ? (fs + (size_t)(b * CCH + srow) * TDIM)
      : (ft + (size_t)(b * CCH + (srow - CCH)) * TDIM))
      + kbase + half * 16;

  f32x4 acc[4][8];
  #pragma unroll
  for (int i = 0; i < 4; ++i)
    #pragma unroll
    for (int j = 0; j < 8; ++j)
      acc[i][j] = (f32x4){0.f, 0.f, 0.f, 0.f};

  // prologue: step 0 -> buf0 directly
  {
    f32x4 v0 = *(const f32x4*)(rp + 0);
    f32x4 v1 = *(const f32x4*)(rp + 4);
    f32x4 v2 = *(const f32x4*)(rp + 8);
    f32x4 v3 = *(const f32x4*)(rp + 12);
    u16x8 pa, pb;
    pa[0]=f2bf(v0.x); pa[1]=f2bf(v0.y); pa[2]=f2bf(v0.z); pa[3]=f2bf(v0.w);
    pa[4]=f2bf(v1.x); pa[5]=f2bf(v1.y); pa[6]=f2bf(v1.z); pa[7]=f2bf(v1.w);
    pb[0]=f2bf(v2.x); pb[1]=f2bf(v2.y); pb[2]=f2bf(v2.z); pb[3]=f2bf(v2.w);
    pb[4]=f2bf(v3.x); pb[5]=f2bf(v3.y); pb[6]=f2bf(v3.z); pb[7]=f2bf(v3.w);
    *(u16x8*)&sm[0][srow][half * 16]     = pa;
    *(u16x8*)&sm[0][srow][half * 16 + 8] = pb;
  }
  f32x4 p[2][4];
  #pragma unroll
  for (int k = 0; k < 4; ++k)
    p[1][k] = *(const f32x4*)(rp + 1 * BK + k * 4);
  __syncthreads();

  #pragma unroll 2
  for (int s = 0; s < NSTEP; ++s) {
    const int par = s & 1;
    if (s + 2 < NSTEP) {
      #pragma unroll
      for (int k = 0; k < 4; ++k)
        p[par][k] = *(const f32x4*)(rp + (s + 2) * BK + k * 4);
    }
    {
      bf16x8 af[4], bfr[8];
      #pragma unroll
      for (int i = 0; i < 4; ++i)
        af[i] = *(const bf16x8*)&sm[par][wr * 64 + i * 16 + llo][koff];
      #pragma unroll
      for (int j = 0; j < 8; ++j)
        bfr[j] = *(const bf16x8*)&sm[par][wc * 128 + j * 16 + llo][koff];
      #pragma unroll
      for (int i = 0; i < 4; ++i)
        #pragma unroll
        for (int j = 0; j < 8; ++j)
          acc[i][j] = __builtin_amdgcn_mfma_f32_16x16x32_bf16(af[i], bfr[j], acc[i][j], 0, 0, 0);
    }
    if (s + 1 < NSTEP) {
      u16x8 pa, pb;
      pa[0]=f2bf(p[par^1][0].x); pa[1]=f2bf(p[par^1][0].y); pa[2]=f2bf(p[par^1][0].z); pa[3]=f2bf(p[par^1][0].w);
      pa[4]=f2bf(p[par^1][1].x); pa[5]=f2bf(p[par^1][1].y); pa[6]=f2bf(p[par^1][1].z); pa[7]=f2bf(p[par^1][1].w);
      pb[0]=f2bf(p[par^1][2].x); pb[1]=f2bf(p[par^1][2].y); pb[2]=f2bf(p[par^1][2].z); pb[3]=f2bf(p[par^1][2].w);
      pb[4]=f2bf(p[par^1][3].x); pb[5]=f2bf(p[par^1][3].y); pb[6]=f2bf(p[par^1][3].z); pb[7]=f2bf(p[par^1][3].w);
      *(u16x8*)&sm[par ^ 1][srow][half * 16]     = pa;
      *(u16x8*)&sm[par ^ 1][srow][half * 16 + 8] = pb;
    }
    __syncthreads();
  }

  // epilogue. C/D layout (m89/m91): col = lane&15, row = (lane>>4)*4 + reg
  float* out = outp + (size_t)sbase * GRAM;
  float* dgp = diagp + (size_t)sbase * MROWS;
  if (atomic) {
    #pragma unroll
    for (int i = 0; i < 4; ++i) {
      int row0 = wr * 64 + i * 16 + lhi * 4;
      #pragma unroll
      for (int j = 0; j < 8; ++j) {
        int col = wc * 128 + j * 16 + llo;
        #pragma unroll
        for (int r = 0; r < 4; ++r)
          atomicAdd(&out[(size_t)(row0 + r) * MROWS + col], acc[i][j][r]);
      }
    }
    if ((wr >> 1) == wc && (llo >> 2) == lhi) {
      #pragma unroll
      for (int i = 0; i < 4; ++i) {
        float dv = acc[i][(wr & 1) * 4 + i][llo & 3];
        atomicAdd(&dgp[wr * 64 + i * 16 + llo], dv);
      }
    }
  } else {
    #pragma unroll
    for (int i = 0; i < 4; ++i) {
      int row0 = wr * 64 + i * 16 + lhi * 4;
      #pragma unroll
      for (int j = 0; j < 8; ++j) {
        int col = wc * 128 + j * 16 + llo;
        #pragma unroll
        for (int r = 0; r < 4; ++r)
          out[(size_t)(row0 + r) * MROWS + col] = acc[i][j][r];
      }
    }
    if ((wr >> 1) == wc && (llo >> 2) == lhi) {
      #pragma unroll
      for (int i = 0; i < 4; ++i) {
        float dv = acc[i][(wr & 1) * 4 + i][llo & 3];
        dgp[wr * 64 + i * 16 + llo] = dv;
      }
    }
  }
}

// grid=BATCH, 256 thr: inverse norms from compact diag partials (coalesced)
__global__ __launch_bounds__(256) void norms_kernel(
    const float* __restrict__ diagp, float* __restrict__ norms, int nchunk)
{
  int b = blockIdx.x;
  int d = threadIdx.x;
  float g = 0.f;
  for (int c = 0; c < nchunk; ++c)
    g += diagp[(b * nchunk + c) * MROWS + d];
  float n = sqrtf(fmaxf(g, 0.f));
  n = fmaxf(n, 1e-12f);
  norms[b * MROWS + d] = 1.0f / n;
}

// Fused partial-reduce + normalize + signed square + global reduce.
__global__ __launch_bounds__(256) void loss_kernel(
    const float* __restrict__ body, const float* __restrict__ norms,
    float* __restrict__ out, int nchunk)
{
  int flat = blockIdx.x * 1024 + threadIdx.x * 4;
  int b    = flat >> 16;
  int e    = flat & 65535;
  const float* nb = norms + b * MROWS;

  f32x4 g = (f32x4){0.f, 0.f, 0.f, 0.f};
  const float* src = body + (size_t)b * nchunk * GRAM + e;
  #pragma unroll 4
  for (int c = 0; c < nchunk; ++c) {
    f32x4 v = *(const f32x4*)(src + (size_t)c * GRAM);
    g.x += v.x; g.y += v.y; g.z += v.z; g.w += v.w;
  }
  int i  = e >> 8;
  int j0 = e & 255;
  float ri = nb[i];
  f32x4 rj = *(const f32x4*)(nb + j0);
  float si = (i < CCH) ? 1.f : -1.f;
  float accl = 0.f;
  #pragma unroll
  for (int q = 0; q < 4; ++q) {
    int j = j0 + q;
    float gh = g[q] * ri * rj[q];
    float sgn = ((j < CCH) ? 1.f : -1.f) * si;
    accl += sgn * gh * gh;
  }
  #pragma unroll
  for (int off = 32; off > 0; off >>= 1)
    accl += __shfl_down(accl, off, 64);
  __shared__ float red[4];
  if ((threadIdx.x & 63) == 0) red[threadIdx.x >> 6] = accl;
  __syncthreads();
  if (threadIdx.x == 0) {
    float t = red[0] + red[1] + red[2] + red[3];
    atomicAdd(out, t * (1.0f / (float)(BATCH * CCH * CCH)));
  }
}

extern "C" void kernel_launch(void* const* d_in, const int* in_sizes, int n_in,
                              void* d_out, int out_size, void* d_ws, size_t ws_size,
                              hipStream_t stream) {
  const float* fs = (const float*)d_in[0];
  const float* ft = (const float*)d_in[1];
  float* out   = (float*)d_out;
  float* wsf   = (float*)d_ws;
  float* norms = wsf + WS_NORMS;
  float* diagp = wsf + WS_DIAG;
  float* body  = wsf + WS_BODY;

  // tier1: 32 partial slots (plain stores)    -> needs ~134.8 MB
  // tier2: 16 slots, chunk-pairs atomicAdd    -> needs ~67.7 MB
  // tier3: 1 slot per batch, all atomicAdd    -> needs ~4.8 MB
  const size_t t1 = (size_t)(WS_BODY + (size_t)BATCH * 32 * GRAM) * 4;
  const size_t t2 = (size_t)(WS_BODY + (size_t)BATCH * 16 * GRAM) * 4;
  int slot_shift, atomic;
  if (ws_size >= t1)      { slot_shift = 0; atomic = 0; }
  else if (ws_size >= t2) { slot_shift = 1; atomic = 1; }
  else                    { slot_shift = 5; atomic = 1; }
  const int nslots = NCHUNK >> slot_shift;

  (void)hipMemsetAsync(d_out, 0, sizeof(float), stream);
  if (atomic) {
    // zero diag + body for all slots in use (contiguous from diagp)
    size_t zb = ((size_t)BATCH * NCHUNK * MROWS
               + (size_t)BATCH * nslots * GRAM) * sizeof(float);
    (void)hipMemsetAsync(diagp, 0, zb, stream);
  }

  gram_kernel<<<dim3(BATCH * NCHUNK), dim3(512), 0, stream>>>(
      fs, ft, body, diagp, slot_shift, atomic);
  // diag partials are per-chunk (NCHUNK) in tier1; per-slot otherwise but
  // zero-padded regions sum correctly only if we sum what was written:
  norms_kernel<<<dim3(BATCH), dim3(256), 0, stream>>>(
      diagp, norms, atomic ? nslots : NCHUNK);
  loss_kernel<<<dim3(1024), dim3(256), 0, stream>>>(body, norms, out, nslots);
}